// Round 11
// baseline (463.084 us; speedup 1.0000x reference)
//
#include <hip/hip_runtime.h>
#include <hip/hip_cooperative_groups.h>
#include <math.h>

namespace cg = cooperative_groups;

// Problem constants (fixed by the reference)
constexpr int M_ROWS    = 16384;
constexpr int N_PTS     = 16384;
constexpr int MAX_EDGES = 4194304;

constexpr int GD     = 10;                       // cells per dim (cell = R = 0.1)
constexpr int NCELLS = GD * GD * GD;             // 1000
constexpr int HBLK   = 64;                       // hist/scatter section blocks (256 pts each)
constexpr int NB     = 512;                      // grid blocks (2/CU, co-resident)
constexpr int TPB    = 256;
constexpr int GSIZE  = NB * TPB;                 // 131072 threads
constexpr int NK     = 27;
constexpr int NTH    = NK * M_ROWS;              // 442368 (q,k) work items

static __device__ __forceinline__ int cell_coord(float v) {
    int c = (int)(v * 10.0f);
    return c < 0 ? 0 : (c > GD - 1 ? GD - 1 : c);
}
static __device__ __forceinline__ int cell_id(float x, float y, float z) {
    return (cell_coord(x) * GD + cell_coord(y)) * GD + cell_coord(z);
}

// Single cooperative kernel, 512 blocks x 256 threads (R10 lesson: the fused
// structure needs R8's parallel work shapes — thread-per-(q,k) count/emit —
// not thread-per-query serial walks; 64 blocks strangled the machine).
// No global atomics; all orders fixed -> deterministic.
__global__ void __launch_bounds__(TPB, 2)
fused_kernel(const float* __restrict__ inp, const float* __restrict__ outp,
             int* __restrict__ H,            // [2*NCELLS][HBLK] counts -> prefixes
             int* __restrict__ cellTot,      // [2048]
             int* __restrict__ cellStart,    // [2][1024]: B at 0, A at 1024
             float4* __restrict__ sortedB, int* __restrict__ sortedJ,
             float4* __restrict__ sortedA, int* __restrict__ sortedRow,
             unsigned char* __restrict__ cnt27, unsigned short* __restrict__ cpfx27,
             int* __restrict__ totals, int* __restrict__ out_idx,
             int* __restrict__ row_splits, float T) {
    cg::grid_group grid = cg::this_grid();
    __shared__ int hb[NCELLS], ha[NCELLS];
    __shared__ int scB[TPB], scA[TPB];
    __shared__ int sp[TPB];
    int b = blockIdx.x, t = threadIdx.x;
    int gtid = b * TPB + t;

    // ---- S1: blocks <HBLK: per-block histograms; others: -1 pre-fill ----
    float bx = 0, by = 0, bz = 0, qx = 0, qy = 0, qz = 0;
    int cidB = 0, cidA = 0;
    if (b < HBLK) {
        for (int i = t; i < NCELLS; i += TPB) { hb[i] = 0; ha[i] = 0; }
        __syncthreads();
        int j = b * TPB + t;                     // 0..16383
        bx = inp[j * 3 + 0]; by = inp[j * 3 + 1]; bz = inp[j * 3 + 2];
        qx = outp[j * 3 + 0]; qy = outp[j * 3 + 1]; qz = outp[j * 3 + 2];
        cidB = cell_id(bx, by, bz);
        cidA = cell_id(qx, qy, qz);
        atomicAdd(&hb[cidB], 1);
        atomicAdd(&ha[cidA], 1);
        __syncthreads();
        for (int i = t; i < NCELLS; i += TPB) {
            H[i * HBLK + b]            = hb[i];
            H[(NCELLS + i) * HBLK + b] = ha[i];
        }
    } else {
        int4* o4 = (int4*)out_idx;
        int n4 = MAX_EDGES / 4;
        for (int i = (b - HBLK) * TPB + t; i < n4; i += (NB - HBLK) * TPB)
            o4[i] = make_int4(-1, -1, -1, -1);
    }
    grid.sync();

    // ---- S2: per-cell prefix over blocks — one wave per (array,cell) ----
    {
        int wid  = b * (TPB / 64) + (t >> 6);    // 0..2047 >= 2000 units
        int lane = t & 63;
        if (wid < 2 * NCELLS) {
            int v = H[wid * HBLK + lane];
            int inc = v;
#pragma unroll
            for (int off = 1; off < 64; off <<= 1) {
                int n = __shfl_up(inc, off, 64);
                if (lane >= off) inc += n;
            }
            H[wid * HBLK + lane] = inc - v;      // exclusive intra-cell prefix
            if (lane == 63) cellTot[wid] = inc;  // cell total
        }
    }
    grid.sync();

    // ---- S2b: block 0 scans cell totals -> cellStartB/A ----
    if (b == 0) {
#pragma unroll 1
        for (int g = 0; g < 2; ++g) {
            int* CS = cellStart + g * 1024;
            int base = g * NCELLS;
            int v[4], pre[4];
            int s = 0;
#pragma unroll
            for (int q = 0; q < 4; ++q) {
                int c = t * 4 + q;
                v[q] = (c < NCELLS) ? cellTot[base + c] : 0;
                pre[q] = s; s += v[q];
            }
            sp[t] = s;
            __syncthreads();
            for (int off = 1; off < TPB; off <<= 1) {
                int n = (t >= off) ? sp[t - off] : 0;
                __syncthreads();
                sp[t] += n;
                __syncthreads();
            }
            int ex = (t == 0) ? 0 : sp[t - 1];
#pragma unroll
            for (int q = 0; q < 4; ++q) {
                int c = t * 4 + q;
                if (c <= NCELLS) CS[c] = ex + pre[q];
            }
            if (t == 255) CS[NCELLS] = sp[255];
            __syncthreads();
        }
    }
    grid.sync();

    // ---- S3: stable scatter (blocks <HBLK; rank via uniform LDS loop) ----
    if (b < HBLK) {
        scB[t] = cidB; scA[t] = cidA;
        __syncthreads();
        int rkB = 0, rkA = 0;
        for (int i = 0; i < TPB - 1; ++i) {      // uniform trip, broadcast reads
            if (i < t) {
                rkB += (scB[i] == cidB);
                rkA += (scA[i] == cidA);
            }
        }
        int j = b * TPB + t;
        float sb2 = __fadd_rn(__fadd_rn(__fmul_rn(bx, bx), __fmul_rn(by, by)), __fmul_rn(bz, bz));
        int posB = cellStart[cidB] + H[cidB * HBLK + b] + rkB;
        sortedB[posB] = make_float4(-2.0f * bx, -2.0f * by, -2.0f * bz, sb2);
        sortedJ[posB] = j;
        float sa2 = __fadd_rn(__fadd_rn(__fmul_rn(qx, qx), __fmul_rn(qy, qy)), __fmul_rn(qz, qz));
        int posA = cellStart[1024 + cidA] + H[(NCELLS + cidA) * HBLK + b] + rkA;
        sortedA[posA] = make_float4(qx, qy, qz, __fsub_rn(T, sa2));
        sortedRow[posA] = j;
    }
    grid.sync();

    // ---- S4: count — thread per (sorted query, neighbor cell), stride ----
    for (int idx = gtid; idx < NTH; idx += GSIZE) {
        int k = idx >> 14, qi = idx & (M_ROWS - 1);
        float4 a = sortedA[qi];
        int cx = cell_coord(a.x) + (k / 9) - 1;
        int cy = cell_coord(a.y) + ((k / 3) % 3) - 1;
        int cz = cell_coord(a.z) + (k % 3) - 1;
        int cnt = 0;
        if (((unsigned)cx < GD) & ((unsigned)cy < GD) & ((unsigned)cz < GD)) {
            int cid = (cx * GD + cy) * GD + cz;
            int s = cellStart[cid], e = cellStart[cid + 1];
            for (int p = s; p < e; ++p) {
                float4 q = sortedB[p];
                float v = __fmaf_rn(a.x, q.x, __fmaf_rn(a.y, q.y, __fmaf_rn(a.z, q.z, q.w)));
                cnt += (v <= a.w);
            }
        }
        cnt27[idx] = (unsigned char)cnt;
    }
    grid.sync();

    // ---- S5: per-query 27-entry prefix + totals (first 16384 threads) ----
    if (gtid < M_ROWS) {
        int qi = gtid;
        int sum = 0;
#pragma unroll
        for (int k = 0; k < NK; ++k) {
            cpfx27[k * M_ROWS + qi] = (unsigned short)sum;
            sum += cnt27[k * M_ROWS + qi];
        }
        totals[sortedRow[qi]] = sum;
    }
    grid.sync();

    // ---- S6: block 0 — global exclusive scan of totals -> row_splits ----
    if (b == 0) {
        const int4* t4 = (const int4*)totals;
        int s = 0;
#pragma unroll 1
        for (int i = 0; i < 16; ++i) {
            int4 v = t4[t * 16 + i];
            s += v.x + v.y + v.z + v.w;
        }
        sp[t] = s;
        __syncthreads();
        for (int off = 1; off < TPB; off <<= 1) {
            int n = (t >= off) ? sp[t - off] : 0;
            __syncthreads();
            sp[t] += n;
            __syncthreads();
        }
        int cur = (t == 0) ? 0 : sp[t - 1];
#pragma unroll 1
        for (int i = 0; i < 16; ++i) {
            int4 v = t4[t * 16 + i];
            row_splits[t * 64 + i * 4 + 0] = cur; cur += v.x;
            row_splits[t * 64 + i * 4 + 1] = cur; cur += v.y;
            row_splits[t * 64 + i * 4 + 2] = cur; cur += v.z;
            row_splits[t * 64 + i * 4 + 3] = cur; cur += v.w;
        }
        if (t == 255) row_splits[M_ROWS] = sp[255];
    }
    grid.sync();

    // ---- S7: emit — thread per (sorted query, neighbor cell), stride ----
    for (int idx = gtid; idx < NTH; idx += GSIZE) {
        int k = idx >> 14, qi = idx & (M_ROWS - 1);
        float4 a = sortedA[qi];
        int cx = cell_coord(a.x) + (k / 9) - 1;
        int cy = cell_coord(a.y) + ((k / 3) % 3) - 1;
        int cz = cell_coord(a.z) + (k % 3) - 1;
        if (((unsigned)cx < GD) & ((unsigned)cy < GD) & ((unsigned)cz < GD)) {
            int cid = (cx * GD + cy) * GD + cz;
            int s = cellStart[cid], e = cellStart[cid + 1];
            int cur = row_splits[sortedRow[qi]] + (int)cpfx27[k * M_ROWS + qi];
            for (int p = s; p < e; ++p) {
                float4 q = sortedB[p];
                float v = __fmaf_rn(a.x, q.x, __fmaf_rn(a.y, q.y, __fmaf_rn(a.z, q.z, q.w)));
                if (v <= a.w) out_idx[cur++] = sortedJ[p];
            }
        }
    }
}

extern "C" void kernel_launch(void* const* d_in, const int* in_sizes, int n_in,
                              void* d_out, int out_size, void* d_ws, size_t ws_size,
                              hipStream_t stream) {
    const float* inp  = (const float*)d_in[0];   // inp_positions [16384,3]
    const float* outp = (const float*)d_in[1];   // out_positions [16384,3]
    int* out_idx    = (int*)d_out;               // [MAX_EDGES]
    int* row_splits = out_idx + MAX_EDGES;       // [M+1]

    char* ws = (char*)d_ws;
    size_t off = 0;
    float4* sortedB = (float4*)(ws + off); off += (size_t)N_PTS * 16;          // 256 KB
    float4* sortedA = (float4*)(ws + off); off += (size_t)M_ROWS * 16;         // 256 KB
    int* H          = (int*)(ws + off);    off += (size_t)2 * NCELLS * HBLK * 4; // 512 KB
    int* cellTot    = (int*)(ws + off);    off += 2048 * 4;
    int* cellStart  = (int*)(ws + off);    off += 2048 * 4;
    int* sortedJ    = (int*)(ws + off);    off += (size_t)N_PTS * 4;           // 64 KB
    int* sortedRow  = (int*)(ws + off);    off += (size_t)M_ROWS * 4;          // 64 KB
    unsigned char*  cnt27  = (unsigned char*)(ws + off);  off += (size_t)NTH;      // 432 KB
    unsigned short* cpfx27 = (unsigned short*)(ws + off); off += (size_t)NTH * 2;  // 864 KB
    int* totals     = (int*)(ws + off);    off += (size_t)M_ROWS * 4;          // 64 KB
    if (off > ws_size) return;  // ~2.5 MB; ws is 256 MB

    // T = largest fp32 strictly below (0.1f + 2^-28)^2: d2<=T <=> sqrt(max(d2,0))<=0.1f
    double md = (double)0.1f + ldexp(1.0, -28);
    double m2 = md * md;
    float  T  = (float)m2;
    if ((double)T >= m2) T = nextafterf(T, 0.0f);

    void* kargs[] = {
        (void*)&inp, (void*)&outp, (void*)&H, (void*)&cellTot, (void*)&cellStart,
        (void*)&sortedB, (void*)&sortedJ, (void*)&sortedA, (void*)&sortedRow,
        (void*)&cnt27, (void*)&cpfx27, (void*)&totals, (void*)&out_idx,
        (void*)&row_splits, (void*)&T
    };
    hipLaunchCooperativeKernel((const void*)fused_kernel, dim3(NB), dim3(TPB),
                               kargs, 0, stream);
}